// Round 5
// baseline (304.924 us; speedup 1.0000x reference)
//
#include <hip/hip_runtime.h>
#include <hip/hip_bf16.h>
#include <cstdint>

// ---------------------------------------------------------------------------
// GraphRLAgent: 2-layer GAT (heads=2 then 1) + global mean pool + 2 heads.
// Round 22: softmax hoisted OUT of the aggregation kernels. bucket_kernel
// (edge-parallel, latency-tolerant) now gathers es1[src], computes per-edge
// w=exp(lrelu(.)), per-dst z via LDS float atomics, and emits NORMALIZED
// csr_alpha (float2, both heads). alpha2_kernel does the same for layer 2
// after the fused GEMM. Agg kernels become pure gather+fma streams with
// 2 nodes/wave (32 lanes = 1 row/load; no cross-lane reductions at all).
// scan_add folded into part_kernel (each block LDS-scans tsum; blk0 emits
// segment bases). Launches stay at 10; h1bf/histscan arrays gone.
// ---------------------------------------------------------------------------

typedef __attribute__((ext_vector_type(8))) short bf16x8;
typedef __attribute__((ext_vector_type(4))) float f32x4;

#define NBLK_H 160   // edge chunks for hist/partition passes
#define BSH 6        // bucket shift: 64 nodes per bucket
#define BMSK 63

__device__ __forceinline__ float wave_sum(float v) {
#pragma unroll
    for (int off = 32; off >= 1; off >>= 1) v += __shfl_xor(v, off, 64);
    return v;
}

__device__ __forceinline__ unsigned short f2bf(float f) {
    union { float f; uint32_t u; } c; c.f = f;
    uint32_t u = c.u;
    return (unsigned short)((u + 0x7fffu + ((u >> 16) & 1u)) >> 16);
}

__device__ __forceinline__ float bf2f(unsigned short u) {
    union { uint32_t u; float f; } c; c.u = ((uint32_t)u) << 16;
    return c.f;
}

// ------------------------- B swizzle body (ldW/colOff aware) --------------

template <int K, int FOUT>
__device__ __forceinline__ void swizzle_body(const float* __restrict__ W, int ldW, int colOff,
                                             unsigned short* __restrict__ Bsw, int tid) {
    constexpr int CPW = FOUT / 4, NCT = CPW / 16, KST = K / 32;
    if (tid >= K * FOUT / 8) return;
    int lane = tid & 63;
    int rest = tid >> 6;
    int t = rest % KST; rest /= KST;
    int c = rest % NCT; rest /= NCT;
    int cg_ = rest;
    int quad = lane >> 4, lo = lane & 15;
    int col = colOff + cg_ * CPW + c * 16 + lo;
    unsigned short v[8];
#pragma unroll
    for (int j = 0; j < 8; ++j)
        v[j] = f2bf(W[(t * 32 + quad * 8 + j) * ldW + col]);
    ushort4* dst = (ushort4*)(Bsw + (size_t)tid * 8);
    ushort4 o0, o1;
    o0.x = v[0]; o0.y = v[1]; o0.z = v[2]; o0.w = v[3];
    o1.x = v[4]; o1.y = v[5]; o1.z = v[6]; o1.w = v[7];
    dst[0] = o0; dst[1] = o1;
}

// ------------------------- init: zero + swizzles + v1 + edge hist ---------

__global__ __launch_bounds__(256) void init_kernel(
        const float* __restrict__ W1, const float* __restrict__ W2,
        const float* __restrict__ a_src1, const float* __restrict__ a_dst1,
        unsigned short* __restrict__ B1h0, unsigned short* __restrict__ B1h1,
        unsigned short* __restrict__ B2,
        float* __restrict__ v1s, float* __restrict__ v1d,
        int* __restrict__ zbase, int zn4, int ZB,
        const int* __restrict__ ei, int* __restrict__ hist,
        int E, int ET, int CHUNK, int NB) {
    __shared__ int bins[1024];
    int b = blockIdx.x;
    if (b < 8)        swizzle_body<128, 128>(W1, 256, 0,   B1h0, b * 256 + threadIdx.x);
    else if (b < 16)  swizzle_body<128, 128>(W1, 256, 128, B1h1, (b - 8) * 256 + threadIdx.x);
    else if (b < 32)  swizzle_body<256, 128>(W2, 128, 0,   B2, (b - 16) * 256 + threadIdx.x);
    else if (b == 32) {
        int t = threadIdx.x, h = t >> 7, k = t & 127;
        float vs = 0.f, vd = 0.f;
        for (int c = 0; c < 128; ++c) {
            float w = W1[k * 256 + h * 128 + c];
            vs += w * a_src1[h * 128 + c];
            vd += w * a_dst1[h * 128 + c];
        }
        v1s[h * 128 + k] = vs;
        v1d[h * 128 + k] = vd;
    } else if (b < 33 + ZB) {
        int i = (b - 33) * 256 + threadIdx.x;
        if (i < zn4) ((int4*)zbase)[i] = make_int4(0, 0, 0, 0);
    } else {
        const int blk = b - 33 - ZB;
        for (int t = threadIdx.x; t < NB; t += 256) bins[t] = 0;
        __syncthreads();
        const int start = blk * CHUNK, end = min(ET, start + CHUNK);
        for (int i = start + threadIdx.x; i < end; i += 256) {
            int dst = (i < E) ? ei[E + i] : (i - E);
            atomicAdd(&bins[dst >> BSH], 1);
        }
        __syncthreads();
        for (int t = threadIdx.x; t < NB; t += 256) hist[t * NBLK_H + blk] = bins[t];
    }
}

// ------------------------- scan_tiles + attn1_cast (fused launch) ---------

__global__ __launch_bounds__(256) void scan_attn1(
        int* __restrict__ hist, int* __restrict__ tsum, int M, int TILESH,
        const float* __restrict__ x, const float* __restrict__ v1s,
        const float* __restrict__ v1d, float* __restrict__ es1,
        float* __restrict__ ed1, unsigned short* __restrict__ xbf, int N) {
    __shared__ int buf[256];
    if ((int)blockIdx.x < TILESH) {
        const int t = threadIdx.x;
        const int base = blockIdx.x * 1024 + t * 4;
        int v[4]; int s = 0;
#pragma unroll
        for (int k = 0; k < 4; ++k) { v[k] = (base + k < M) ? hist[base + k] : 0; s += v[k]; }
        buf[t] = s;
        __syncthreads();
#pragma unroll
        for (int off = 1; off < 256; off <<= 1) {
            int xx = (t >= off) ? buf[t - off] : 0;
            __syncthreads();
            buf[t] += xx;
            __syncthreads();
        }
        int run = buf[t] - s;
#pragma unroll
        for (int k = 0; k < 4; ++k) {
            if (base + k < M) hist[base + k] = run;
            run += v[k];
        }
        if (t == 255) tsum[blockIdx.x] = buf[255];
        return;
    }
    int bid = blockIdx.x - TILESH;
    int wid = (bid * 256 + threadIdx.x) >> 6;
    int lane = threadIdx.x & 63;
    if (wid >= N) return;
    float2 xv = *(const float2*)(x + (size_t)wid * 128 + lane * 2);
    float p0s = xv.x * v1s[lane * 2] + xv.y * v1s[lane * 2 + 1];
    float p1s = xv.x * v1s[128 + lane * 2] + xv.y * v1s[128 + lane * 2 + 1];
    float p0d = xv.x * v1d[lane * 2] + xv.y * v1d[lane * 2 + 1];
    float p1d = xv.x * v1d[128 + lane * 2] + xv.y * v1d[128 + lane * 2 + 1];
    p0s = wave_sum(p0s); p1s = wave_sum(p1s);
    p0d = wave_sum(p0d); p1d = wave_sum(p1d);
    if (lane == 0) {
        es1[wid * 2] = p0s; es1[wid * 2 + 1] = p1s;
        ed1[wid * 2] = p0d; ed1[wid * 2 + 1] = p1d;
    }
    ushort2 o; o.x = f2bf(xv.x); o.y = f2bf(xv.y);
    *(ushort2*)(xbf + (size_t)wid * 128 + lane * 2) = o;
}

// ------------------------- partition (folds global scan) ------------------
// Each block: LDS-scan tsum (T<=256), rebuild its scur column from the
// tile-scanned hist, then scatter its edge chunk. Block 0 also emits
// segbase[0..NB] for bucket_kernel.

__global__ __launch_bounds__(256) void part_kernel(const int* __restrict__ ei,
                                                   const int* __restrict__ hist,
                                                   const int* __restrict__ tsum,
                                                   int* __restrict__ bsorted,
                                                   int* __restrict__ segbase,
                                                   int E, int ET, int CHUNK, int NB, int T) {
    __shared__ int sb[256];
    __shared__ int scur[1024];
    const int t = threadIdx.x;
    sb[t] = (t < T) ? tsum[t] : 0;
    __syncthreads();
#pragma unroll
    for (int off = 1; off < 256; off <<= 1) {
        int v = (t >= off) ? sb[t - off] : 0;
        __syncthreads();
        sb[t] += v;
        __syncthreads();
    }
    const int blk = blockIdx.x;
    for (int b = t; b < NB; b += 256) {
        int idx = b * NBLK_H + blk;
        int tile = idx >> 10;
        int v = hist[idx] + (tile ? sb[tile - 1] : 0);
        scur[b] = v;
        if (blk == 0) segbase[b] = v;
    }
    if (blk == 0 && t == 0) segbase[NB] = sb[T - 1];
    __syncthreads();
    const int start = blk * CHUNK, end = min(ET, start + CHUNK);
    for (int i = start + t; i < end; i += 256) {
        int dst = (i < E) ? ei[E + i] : (i - E);
        int src = (i < E) ? ei[i] : dst;
        int pos = atomicAdd(&scur[dst >> BSH], 1);
        bsorted[pos] = (src << BSH) | (dst & BMSK);
    }
}

// ------------------------- bucket sort + layer-1 softmax ------------------
// Per-bucket (64 dst nodes) counting sort emitting rowptr + csr_src, PLUS
// the layer-1 attention softmax: gather es1[src], w=exp(lrelu(e)), per-dst z
// via LDS float atomics, emit NORMALIZED csr_alpha (float2 = both heads).

__global__ __launch_bounds__(256) void bucket_kernel(const int* __restrict__ bsorted,
                                                     const int* __restrict__ segbase,
                                                     const float* __restrict__ es1,
                                                     const float* __restrict__ ed1,
                                                     int* __restrict__ csr_src,
                                                     float2* __restrict__ csr_alpha,
                                                     int* __restrict__ rowptr,
                                                     int N, int NB) {
    __shared__ int cnt[64], excl[64];
    __shared__ float z0[64], z1[64];
    __shared__ float2 edv[64];
    __shared__ int ebuf[3072];
    __shared__ float2 wbuf[3072];
    const int b = blockIdx.x;
    const int gbase = segbase[b], gend = segbase[b + 1];
    const int sz = gend - gbase;
    const int t = threadIdx.x;
    if (b == 0 && t == 0) rowptr[N] = segbase[NB];
    if (t < 64) {
        cnt[t] = 0; z0[t] = 0.f; z1[t] = 0.f;
        int dst = (b << BSH) + t;
        if (dst < N) edv[t] = *(const float2*)(ed1 + dst * 2);
        else edv[t] = make_float2(0.f, 0.f);
    }
    __syncthreads();
    const bool fits = (sz <= 3072);
    for (int i = t; i < sz; i += 256) {
        int p = bsorted[gbase + i];
        int s = p >> BSH, ld = p & BMSK;
        float2 esv = *(const float2*)(es1 + s * 2);
        float e0 = esv.x + edv[ld].x; e0 = (e0 > 0.f) ? e0 : 0.2f * e0;
        float e1 = esv.y + edv[ld].y; e1 = (e1 > 0.f) ? e1 : 0.2f * e1;
        float w0 = __expf(e0), w1 = __expf(e1);
        if (fits) { ebuf[i] = p; wbuf[i] = make_float2(w0, w1); }
        atomicAdd(&z0[ld], w0);
        atomicAdd(&z1[ld], w1);
        atomicAdd(&cnt[ld], 1);
    }
    __syncthreads();
    if (t < 64) excl[t] = cnt[t];
    __syncthreads();
    for (int off = 1; off < 64; off <<= 1) {
        int v = (t < 64 && t >= off) ? excl[t - off] : 0;
        __syncthreads();
        if (t < 64) excl[t] += v;
        __syncthreads();
    }
    if (t < 64) {
        int dst = (b << BSH) + t;
        if (dst < N) rowptr[dst] = gbase + excl[t] - cnt[t];
    }
    __syncthreads();
    if (t < 64) {
        cnt[t] = excl[t] - cnt[t];   // running cursor
        z0[t] = 1.f / (z0[t] + 1e-16f);
        z1[t] = 1.f / (z1[t] + 1e-16f);
    }
    __syncthreads();
    if (fits) {
        for (int i = t; i < sz; i += 256) {
            int p = ebuf[i]; float2 wv = wbuf[i];
            int ld = p & BMSK;
            int pos = atomicAdd(&cnt[ld], 1);
            csr_src[gbase + pos] = p >> BSH;
            csr_alpha[gbase + pos] = make_float2(wv.x * z0[ld], wv.y * z1[ld]);
        }
    } else {
        for (int i = t; i < sz; i += 256) {
            int p = bsorted[gbase + i];
            int s = p >> BSH, ld = p & BMSK;
            float2 esv = *(const float2*)(es1 + s * 2);
            float e0 = esv.x + edv[ld].x; e0 = (e0 > 0.f) ? e0 : 0.2f * e0;
            float e1 = esv.y + edv[ld].y; e1 = (e1 > 0.f) ? e1 : 0.2f * e1;
            float w0 = __expf(e0), w1 = __expf(e1);
            int pos = atomicAdd(&cnt[ld], 1);
            csr_src[gbase + pos] = s;
            csr_alpha[gbase + pos] = make_float2(w0 * z0[ld], w1 * z1[ld]);
        }
    }
}

// ------------------------- layer-1 aggregation (pure gather) --------------
// 2 nodes per wave (32 lanes each; lane's 8B block covers the full 256B row
// across the group). No softmax work: alpha is precomputed & normalized.
// NOTE: macro params must not be named x/y/z/w (token substitution).

#define ACC2(U_, WW_, P_, Q_) { float v_;                              \
    v_ = bf2f(U_.x); P_.x += WW_.x * v_; Q_.x += WW_.y * v_;           \
    v_ = bf2f(U_.y); P_.y += WW_.x * v_; Q_.y += WW_.y * v_;           \
    v_ = bf2f(U_.z); P_.z += WW_.x * v_; Q_.z += WW_.y * v_;           \
    v_ = bf2f(U_.w); P_.w += WW_.x * v_; Q_.w += WW_.y * v_; }

__global__ void gat_agg_x(const unsigned short* __restrict__ xbf,
                          const int* __restrict__ rowptr, const int* __restrict__ csr_src,
                          const float2* __restrict__ csr_alpha,
                          unsigned short* __restrict__ aggx, int N, int NPAD) {
    __shared__ int    s_lds[4][2][32];
    __shared__ float2 a_lds[4][2][32];
    const int wave = threadIdx.x >> 6, lane = threadIdx.x & 63;
    const int g = lane >> 5, c = lane & 31;
    const int node = (blockIdx.x * 4 + wave) * 2 + g;
    if (node >= N) return;
    const int rs = rowptr[node], re = rowptr[node + 1];
    float4 p = {0.f, 0.f, 0.f, 0.f}, q = {0.f, 0.f, 0.f, 0.f};
    for (int i = rs; i < re; i += 32) {
        const int cnt = min(re - i, 32);
        if (c < cnt) {
            s_lds[wave][g][c] = csr_src[i + c];
            a_lds[wave][g][c] = csr_alpha[i + c];
        }
        // same-wave LDS RAW: compiler inserts lgkmcnt wait
        int k = 0;
        for (; k + 7 < cnt; k += 8) {
            int s0 = s_lds[wave][g][k + 0], s1 = s_lds[wave][g][k + 1];
            int s2 = s_lds[wave][g][k + 2], s3 = s_lds[wave][g][k + 3];
            int s4 = s_lds[wave][g][k + 4], s5 = s_lds[wave][g][k + 5];
            int s6 = s_lds[wave][g][k + 6], s7 = s_lds[wave][g][k + 7];
            float2 a0 = a_lds[wave][g][k + 0], a1 = a_lds[wave][g][k + 1];
            float2 a2 = a_lds[wave][g][k + 2], a3 = a_lds[wave][g][k + 3];
            float2 a4 = a_lds[wave][g][k + 4], a5 = a_lds[wave][g][k + 5];
            float2 a6 = a_lds[wave][g][k + 6], a7 = a_lds[wave][g][k + 7];
            ushort4 u0 = *(const ushort4*)(xbf + (size_t)s0 * 128 + c * 4);
            ushort4 u1 = *(const ushort4*)(xbf + (size_t)s1 * 128 + c * 4);
            ushort4 u2 = *(const ushort4*)(xbf + (size_t)s2 * 128 + c * 4);
            ushort4 u3 = *(const ushort4*)(xbf + (size_t)s3 * 128 + c * 4);
            ushort4 u4 = *(const ushort4*)(xbf + (size_t)s4 * 128 + c * 4);
            ushort4 u5 = *(const ushort4*)(xbf + (size_t)s5 * 128 + c * 4);
            ushort4 u6 = *(const ushort4*)(xbf + (size_t)s6 * 128 + c * 4);
            ushort4 u7 = *(const ushort4*)(xbf + (size_t)s7 * 128 + c * 4);
            ACC2(u0, a0, p, q);
            ACC2(u1, a1, p, q);
            ACC2(u2, a2, p, q);
            ACC2(u3, a3, p, q);
            ACC2(u4, a4, p, q);
            ACC2(u5, a5, p, q);
            ACC2(u6, a6, p, q);
            ACC2(u7, a7, p, q);
        }
        for (; k < cnt; ++k) {
            int s0 = s_lds[wave][g][k];
            float2 a0 = a_lds[wave][g][k];
            ushort4 u0 = *(const ushort4*)(xbf + (size_t)s0 * 128 + c * 4);
            ACC2(u0, a0, p, q);
        }
    }
    ushort4 o;
    o.x = f2bf(p.x); o.y = f2bf(p.y); o.z = f2bf(p.z); o.w = f2bf(p.w);
    *(ushort4*)(aggx + (size_t)node * 128 + c * 4) = o;
    o.x = f2bf(q.x); o.y = f2bf(q.y); o.z = f2bf(q.z); o.w = f2bf(q.w);
    *(ushort4*)(aggx + (size_t)NPAD * 128 + (size_t)node * 128 + c * 4) = o;
}

// ------------------------- fused layer-1 + layer-2 GEMM -------------------

__global__ __launch_bounds__(256) void gemm12_fused(
        const unsigned short* __restrict__ Abase,
        const unsigned short* __restrict__ B1h0, const unsigned short* __restrict__ B1h1,
        const unsigned short* __restrict__ B2sw,
        const float* __restrict__ b1,
        const float* __restrict__ a_src, const float* __restrict__ a_dst,
        float* __restrict__ es, float* __restrict__ ed,
        unsigned short* __restrict__ C, int N, int NPAD) {
    __shared__ unsigned short h1t[64][264];
    __shared__ float lds_ps[4][64];
    __shared__ float lds_pd[4][64];
    const int tid = threadIdx.x;
    const int wave = tid >> 6, lane = tid & 63;
    const int quad = lane >> 4, lo = lane & 15;
    const int n0 = blockIdx.x * 64;

    {
        const int head = wave >> 1, wh = wave & 1;
        const unsigned short* A = Abase + (size_t)head * NPAD * 128;
        const bf16x8* Bp = (const bf16x8*)(head ? B1h1 : B1h0);
        bf16x8 bf[4][4];
#pragma unroll
        for (int c = 0; c < 4; ++c)
#pragma unroll
            for (int t = 0; t < 4; ++t)
                bf[c][t] = Bp[((wh * 4 + c) * 4 + t) * 64 + lane];
        f32x4 acc[4][4];
#pragma unroll
        for (int r = 0; r < 4; ++r)
#pragma unroll
            for (int c = 0; c < 4; ++c) acc[r][c] = (f32x4){0.f, 0.f, 0.f, 0.f};
#pragma unroll
        for (int r = 0; r < 4; ++r) {
            const unsigned short* Ar = A + (size_t)(n0 + r * 16 + lo) * 128 + quad * 8;
#pragma unroll
            for (int t = 0; t < 4; ++t) {
                bf16x8 af = *(const bf16x8*)(Ar + t * 32);
#pragma unroll
                for (int c = 0; c < 4; ++c)
                    acc[r][c] = __builtin_amdgcn_mfma_f32_16x16x32_bf16(af, bf[c][t],
                                                                       acc[r][c], 0, 0, 0);
            }
        }
#pragma unroll
        for (int r = 0; r < 4; ++r) {
            int rl = r * 16 + quad * 4;
#pragma unroll
            for (int c = 0; c < 4; ++c) {
                int col = head * 128 + wh * 64 + c * 16 + lo;
                float bv = b1[col];
#pragma unroll
                for (int j = 0; j < 4; ++j) {
                    float v = acc[r][c][j] + bv;
                    v = (v > 0.f) ? v : __expf(v) - 1.f;
                    h1t[rl + j][col] = f2bf(v);
                }
            }
        }
    }
    __syncthreads();

    bf16x8 bf2[2][8];
    {
        const bf16x8* Bp2 = (const bf16x8*)B2sw;
#pragma unroll
        for (int c = 0; c < 2; ++c)
#pragma unroll
            for (int t = 0; t < 8; ++t)
                bf2[c][t] = Bp2[((wave * 2 + c) * 8 + t) * 64 + lane];
    }
    f32x4 acc2[4][2];
#pragma unroll
    for (int r = 0; r < 4; ++r)
#pragma unroll
        for (int c = 0; c < 2; ++c) acc2[r][c] = (f32x4){0.f, 0.f, 0.f, 0.f};
#pragma unroll
    for (int r = 0; r < 4; ++r) {
        const unsigned short* Ar = &h1t[r * 16 + lo][quad * 8];
#pragma unroll
        for (int t = 0; t < 8; ++t) {
            bf16x8 af = *(const bf16x8*)(Ar + t * 32);
#pragma unroll
            for (int c = 0; c < 2; ++c)
                acc2[r][c] = __builtin_amdgcn_mfma_f32_16x16x32_bf16(af, bf2[c][t],
                                                                    acc2[r][c], 0, 0, 0);
        }
    }
    const int c0 = wave * 32;
#pragma unroll
    for (int r = 0; r < 4; ++r) {
        int row = n0 + r * 16 + quad * 4;
#pragma unroll
        for (int c = 0; c < 2; ++c) {
            int col = c0 + c * 16 + lo;
#pragma unroll
            for (int j = 0; j < 4; ++j)
                if (row + j < N) C[(size_t)(row + j) * 128 + col] = f2bf(acc2[r][c][j]);
        }
    }
    float asv[2], adv[2];
#pragma unroll
    for (int c = 0; c < 2; ++c) {
        int col = c0 + c * 16 + lo;
        asv[c] = a_src[col];
        adv[c] = a_dst[col];
    }
#pragma unroll
    for (int r = 0; r < 4; ++r) {
#pragma unroll
        for (int j = 0; j < 4; ++j) {
            float ps = 0.f, pd = 0.f;
#pragma unroll
            for (int c = 0; c < 2; ++c) { ps += acc2[r][c][j] * asv[c]; pd += acc2[r][c][j] * adv[c]; }
#pragma unroll
            for (int off = 1; off <= 8; off <<= 1) {
                ps += __shfl_xor(ps, off, 64);
                pd += __shfl_xor(pd, off, 64);
            }
            if (lo == 0) {
                int row_l = r * 16 + quad * 4 + j;
                lds_ps[wave][row_l] = ps;
                lds_pd[wave][row_l] = pd;
            }
        }
    }
    __syncthreads();
    if (tid < 64) {
        int row = tid;
        int n = n0 + row;
        if (n < N) {
            es[n] = lds_ps[0][row] + lds_ps[1][row] + lds_ps[2][row] + lds_ps[3][row];
            ed[n] = lds_pd[0][row] + lds_pd[1][row] + lds_pd[2][row] + lds_pd[3][row];
        }
    }
}

// ------------------------- layer-2 alpha precompute -----------------------
// Wave per node; edges 64-wide parallel. Emits normalized csr_a2.

__global__ void alpha2_kernel(const int* __restrict__ rowptr, const int* __restrict__ csr_src,
                              const float* __restrict__ es, const float* __restrict__ ed,
                              float* __restrict__ csr_a2, int N) {
    int wid = (blockIdx.x * blockDim.x + threadIdx.x) >> 6;
    int lane = threadIdx.x & 63;
    if (wid >= N) return;
    const int rs = rowptr[wid], re = rowptr[wid + 1];
    const float edn = ed[wid];
    float z = 0.f;
    for (int i = rs; i < re; i += 64) {
        int cnt = min(re - i, 64);
        if (lane < cnt) {
            int s = csr_src[i + lane];
            float e = es[s] + edn;
            e = (e > 0.f) ? e : 0.2f * e;
            float w = __expf(e);
            csr_a2[i + lane] = w;
            z += w;
        }
    }
    z = wave_sum(z);
    const float rz = 1.f / (z + 1e-16f);
    for (int i = rs + lane; i < re; i += 64) csr_a2[i] *= rz;
}

// ------------------------- layer-2 aggregation (pure gather) --------------

#define ACC1(U_, W_, P_) {                                   \
    P_.x += W_ * bf2f(U_.x); P_.y += W_ * bf2f(U_.y);        \
    P_.z += W_ * bf2f(U_.z); P_.w += W_ * bf2f(U_.w); }

__global__ void gat_agg_h1(const unsigned short* __restrict__ Hpre,
                           const int* __restrict__ rowptr, const int* __restrict__ csr_src,
                           const float* __restrict__ csr_a2,
                           const float* __restrict__ bias, unsigned short* __restrict__ out,
                           int N) {
    __shared__ int   s_lds[4][2][32];
    __shared__ float a_lds[4][2][32];
    const int wave = threadIdx.x >> 6, lane = threadIdx.x & 63;
    const int g = lane >> 5, c = lane & 31;
    const int node = (blockIdx.x * 4 + wave) * 2 + g;
    if (node >= N) return;
    const int rs = rowptr[node], re = rowptr[node + 1];
    float4 p = {0.f, 0.f, 0.f, 0.f};
    for (int i = rs; i < re; i += 32) {
        const int cnt = min(re - i, 32);
        if (c < cnt) {
            s_lds[wave][g][c] = csr_src[i + c];
            a_lds[wave][g][c] = csr_a2[i + c];
        }
        // same-wave LDS RAW: compiler inserts lgkmcnt wait
        int k = 0;
        for (; k + 7 < cnt; k += 8) {
            int s0 = s_lds[wave][g][k + 0], s1 = s_lds[wave][g][k + 1];
            int s2 = s_lds[wave][g][k + 2], s3 = s_lds[wave][g][k + 3];
            int s4 = s_lds[wave][g][k + 4], s5 = s_lds[wave][g][k + 5];
            int s6 = s_lds[wave][g][k + 6], s7 = s_lds[wave][g][k + 7];
            float a0 = a_lds[wave][g][k + 0], a1 = a_lds[wave][g][k + 1];
            float a2 = a_lds[wave][g][k + 2], a3 = a_lds[wave][g][k + 3];
            float a4 = a_lds[wave][g][k + 4], a5 = a_lds[wave][g][k + 5];
            float a6 = a_lds[wave][g][k + 6], a7 = a_lds[wave][g][k + 7];
            ushort4 u0 = *(const ushort4*)(Hpre + (size_t)s0 * 128 + c * 4);
            ushort4 u1 = *(const ushort4*)(Hpre + (size_t)s1 * 128 + c * 4);
            ushort4 u2 = *(const ushort4*)(Hpre + (size_t)s2 * 128 + c * 4);
            ushort4 u3 = *(const ushort4*)(Hpre + (size_t)s3 * 128 + c * 4);
            ushort4 u4 = *(const ushort4*)(Hpre + (size_t)s4 * 128 + c * 4);
            ushort4 u5 = *(const ushort4*)(Hpre + (size_t)s5 * 128 + c * 4);
            ushort4 u6 = *(const ushort4*)(Hpre + (size_t)s6 * 128 + c * 4);
            ushort4 u7 = *(const ushort4*)(Hpre + (size_t)s7 * 128 + c * 4);
            ACC1(u0, a0, p);
            ACC1(u1, a1, p);
            ACC1(u2, a2, p);
            ACC1(u3, a3, p);
            ACC1(u4, a4, p);
            ACC1(u5, a5, p);
            ACC1(u6, a6, p);
            ACC1(u7, a7, p);
        }
        for (; k < cnt; ++k) {
            int s0 = s_lds[wave][g][k];
            float a0 = a_lds[wave][g][k];
            ushort4 u0 = *(const ushort4*)(Hpre + (size_t)s0 * 128 + c * 4);
            ACC1(u0, a0, p);
        }
    }
    float4 bv = ((const float4*)bias)[c];
    float ox = p.x + bv.x, oy = p.y + bv.y, oz = p.z + bv.z, ow = p.w + bv.w;
    ox = (ox > 0.f) ? ox : __expf(ox) - 1.f;
    oy = (oy > 0.f) ? oy : __expf(oy) - 1.f;
    oz = (oz > 0.f) ? oz : __expf(oz) - 1.f;
    ow = (ow > 0.f) ? ow : __expf(ow) - 1.f;
    ushort4 o;
    o.x = f2bf(ox); o.y = f2bf(oy); o.z = f2bf(oz); o.w = f2bf(ow);
    *(ushort4*)(out + (size_t)node * 128 + c * 4) = o;
}

// ------------------------- global mean pool (chunk-parallel) --------------

#define PCHUNK 256

__global__ __launch_bounds__(256) void pool_partial(const unsigned short* __restrict__ h2,
                                                    const int* __restrict__ batch,
                                                    float* __restrict__ xsum,
                                                    int* __restrict__ cnt, int N) {
    const int base = blockIdx.x * PCHUNK;
    const int rg = threadIdx.x >> 6;
    const int c2 = threadIdx.x & 63;
    float ax = 0.f, ay = 0.f;
    int gcur = -1, run = 0;
    for (int r = rg; r < PCHUNK; r += 4) {
        int i = base + r;
        if (i >= N) break;
        int g = batch[i];
        if (g != gcur) {
            if (gcur >= 0) {
                atomicAdd(&xsum[gcur * 128 + c2 * 2 + 0], ax);
                atomicAdd(&xsum[gcur * 128 + c2 * 2 + 1], ay);
                if (c2 == 0) atomicAdd(&cnt[gcur], run);
            }
            gcur = g; ax = 0.f; ay = 0.f; run = 0;
        }
        ushort2 u = *(const ushort2*)(h2 + (size_t)i * 128 + c2 * 2);
        ax += bf2f(u.x); ay += bf2f(u.y);
        run += 1;
    }
    if (gcur >= 0) {
        atomicAdd(&xsum[gcur * 128 + c2 * 2 + 0], ax);
        atomicAdd(&xsum[gcur * 128 + c2 * 2 + 1], ay);
        if (c2 == 0) atomicAdd(&cnt[gcur], run);
    }
}

// ------------------------- policy / value heads ---------------------------

__global__ void head_kernel(const float* __restrict__ xsum, const int* __restrict__ cnt,
                            const float* __restrict__ Wp, const float* __restrict__ bp,
                            const float* __restrict__ Wv, const float* __restrict__ bv,
                            float* __restrict__ out) {
    int g = blockIdx.x, t = threadIdx.x;  // 64 threads
    __shared__ float p[128];
    float inv = 1.f / fmaxf((float)cnt[g], 1.f);
    p[t] = xsum[g * 128 + t] * inv;
    p[t + 64] = xsum[g * 128 + t + 64] * inv;
    __syncthreads();
    if (t < 32) {
        float acc = bp[t];
        for (int k = 0; k < 128; ++k) acc += p[k] * Wp[k * 32 + t];
        out[g * 32 + t] = acc;
    } else if (t == 32) {
        float acc = bv[0];
        for (int k = 0; k < 128; ++k) acc += p[k] * Wv[k];
        out[64 * 32 + g] = acc;
    }
}

// ---------------------------------------------------------------------------

extern "C" void kernel_launch(void* const* d_in, const int* in_sizes, int n_in,
                              void* d_out, int out_size, void* d_ws, size_t ws_size,
                              hipStream_t stream) {
    const float* x      = (const float*)d_in[0];
    const int*   ei     = (const int*)d_in[1];
    const int*   batch  = (const int*)d_in[2];
    const float* W1     = (const float*)d_in[3];
    const float* a_src1 = (const float*)d_in[4];
    const float* a_dst1 = (const float*)d_in[5];
    const float* b1     = (const float*)d_in[6];
    const float* W2     = (const float*)d_in[7];
    const float* a_src2 = (const float*)d_in[8];
    const float* a_dst2 = (const float*)d_in[9];
    const float* b2     = (const float*)d_in[10];
    const float* Wp     = (const float*)d_in[11];
    const float* bp     = (const float*)d_in[12];
    const float* Wv     = (const float*)d_in[13];
    const float* bv     = (const float*)d_in[14];

    const int N  = in_sizes[0] / 128;
    const int E  = in_sizes[1] / 2;
    const int ET = E + N;
    const int NPAD = ((N + 63) / 64) * 64;
    const int NBLK = NPAD / 64;
    const int PBLK = (N + PCHUNK - 1) / PCHUNK;
    const int NB = (N + 63) >> BSH;
    const int CHUNK = (ET + NBLK_H - 1) / NBLK_H;
    const int M = NB * NBLK_H;
    const int TILESH = (M + 1023) / 1024;           // <=256
    const int AB = (N + 3) / 4;
    const int GB = (N + 7) / 8;                     // agg blocks (8 nodes each)

    char* ws = (char*)d_ws;
    size_t off = 0;
    auto alloc = [&](size_t bytes) -> void* {
        void* p = ws + off;
        off = (off + bytes + 255) & ~(size_t)255;
        return p;
    };
    unsigned short* xbf   = (unsigned short*)alloc((size_t)NPAD * 128 * 2);
    unsigned short* aggx  = (unsigned short*)alloc((size_t)2 * NPAD * 128 * 2);
    unsigned short* h2pre = (unsigned short*)alloc((size_t)NPAD * 128 * 2);
    unsigned short* h2bf  = (unsigned short*)alloc((size_t)N * 128 * 2);
    unsigned short* w1h0  = (unsigned short*)alloc((size_t)128 * 128 * 2);
    unsigned short* w1h1  = (unsigned short*)alloc((size_t)128 * 128 * 2);
    unsigned short* w2sw  = (unsigned short*)alloc((size_t)256 * 128 * 2);
    float* v1s = (float*)alloc(256 * 4);
    float* v1d = (float*)alloc(256 * 4);
    float* es1 = (float*)alloc((size_t)N * 2 * 4);
    float* ed1 = (float*)alloc((size_t)N * 2 * 4);
    float* es2 = (float*)alloc((size_t)N * 4);
    float* ed2 = (float*)alloc((size_t)N * 4);
    // contiguous zero region: xsum | cnt
    const int ZINTS = 64 * 128 + 64;
    int*   zbase  = (int*)alloc(((size_t)ZINTS + 8) * 4);
    float* xsum   = (float*)zbase;
    int*   cnt    = (int*)(xsum + 64 * 128);
    int*    rowptr    = (int*)alloc((size_t)(N + 1) * 4);
    int*    hist      = (int*)alloc((size_t)M * 4);
    int*    segbase   = (int*)alloc((size_t)(NB + 1) * 4);
    int*    bsorted   = (int*)alloc((size_t)ET * 4);
    int*    csrsrc    = (int*)alloc((size_t)ET * 4);
    float2* csralpha  = (float2*)alloc((size_t)ET * 8);
    float*  csra2     = (float*)alloc((size_t)ET * 4);
    int*    tsum      = (int*)alloc(256 * 4);
    const int zn4 = (ZINTS + 3) / 4;
    const int ZB = (zn4 + 255) / 256;

    // 1. init: swizzles + v1 + zero + edge histogram
    init_kernel<<<33 + ZB + NBLK_H, 256, 0, stream>>>(W1, W2, a_src1, a_dst1,
                                                      w1h0, w1h1, w2sw, v1s, v1d,
                                                      zbase, zn4, ZB,
                                                      ei, hist, E, ET, CHUNK, NB);
    // 2. hist tile-scan + attn1 coefs + x cast
    scan_attn1<<<TILESH + AB, 256, 0, stream>>>(hist, tsum, M, TILESH,
                                                x, v1s, v1d, es1, ed1, xbf, N);
    // 3. partition (folds global scan; blk0 emits segbase)
    part_kernel<<<NBLK_H, 256, 0, stream>>>(ei, hist, tsum, bsorted, segbase,
                                            E, ET, CHUNK, NB, TILESH);
    // 4. bucket sort + layer-1 softmax -> rowptr, csr_src, csr_alpha
    bucket_kernel<<<NB, 256, 0, stream>>>(bsorted, segbase, es1, ed1,
                                          csrsrc, csralpha, rowptr, N, NB);
    // 5. layer-1 aggregation (pure gather, 2 nodes/wave)
    gat_agg_x<<<GB, 256, 0, stream>>>(xbf, rowptr, csrsrc, csralpha, aggx, N, NPAD);
    // 6. fused layer-1 + layer-2 GEMM (+es2/ed2 epilogue)
    gemm12_fused<<<NBLK, 256, 0, stream>>>(aggx, w1h0, w1h1, w2sw, b1,
                                           a_src2, a_dst2, es2, ed2, h2pre, N, NPAD);
    // 7. layer-2 alpha precompute
    alpha2_kernel<<<AB, 256, 0, stream>>>(rowptr, csrsrc, es2, ed2, csra2, N);
    // 8. layer-2 aggregation (pure gather, 2 nodes/wave)
    gat_agg_h1<<<GB, 256, 0, stream>>>(h2pre, rowptr, csrsrc, csra2, b2, h2bf, N);
    // 9/10. pool + heads
    pool_partial<<<PBLK, 256, 0, stream>>>(h2bf, batch, xsum, cnt, N);
    head_kernel<<<64, 64, 0, stream>>>(xsum, cnt, Wp, bp, Wv, bv, (float*)d_out);
}